// Round 4
// baseline (346.414 us; speedup 1.0000x reference)
//
#include <hip/hip_runtime.h>

#define T_STEPS 100
#define CHUNKS  25    // 100 floats = 25 float4 per element
#define TPB     64    // one wave per block
#define ELEMS   64    // elements per block (== TPB)
// LDS: 64 * 25 float4 * 16B = 25600 B -> 6 blocks/CU (153.6/160 KB)

// Hybrid structure:
//   loads:   per-lane strided float4 -> REGISTERS (compiler emits fine-grained
//            vmcnt(N) per-use waits; no vmcnt(0) convoy like global_load_lds).
//            Read path is HBM-clean (R1: FETCH ~149MB, L1 catches the 4x line
//            reuse within a wave's 25.6KB tile).
//   compute: pure-register recurrence (no LDS latency in the serial chain).
//   stores:  one LDS transpose (write own row b128, read stride-1 b128, both
//            the same 8-lanes-per-bank-group pattern as stride-1 = baseline
//            rate), then coalesced full-line float4 global stores (keeps
//            WRITE_SIZE at the ideal 210MB; R1's strided stores paid 1.45x).
//
// NUMERICS: bit-identical to numpy reference (verified R1/R2/R3, absmax 0):
//   fp contract OFF; op order ((mem*TAU)+x)-w ; (BETA*w)+(1-BETA)*((A*m)+(B*s));
//   mem - spike*THRESH ; BETA->0.9f, (1-BETA)->0.1f ; *0.5f exact (exp shift).
__global__ __launch_bounds__(TPB) void lif_kernel(const float* __restrict__ x,
                                                  float* __restrict__ out) {
#pragma clang fp contract(off)
    __shared__ float4 tile[ELEMS * CHUNKS];

    const int lane = threadIdx.x;
    const size_t tile4 = (size_t)blockIdx.x * (ELEMS * CHUNKS);
    const float4* __restrict__ xp = (const float4*)x + tile4 + (size_t)lane * CHUNKS;
    float4* __restrict__ ob = (float4*)out + tile4;

    // ---- load: own element's 25 float4 chunks straight to registers ------
    float4 xs[CHUNKS];
#pragma unroll
    for (int c = 0; c < CHUNKS; ++c) xs[c] = xp[c];

    // ---- compute: register-resident recurrence, spikes overwrite xs ------
    {
        float mem = 0.0f;
        float w = 0.0f;
#pragma unroll
        for (int c = 0; c < CHUNKS; ++c) {
            float xv[4] = {xs[c].x, xs[c].y, xs[c].z, xs[c].w};
            float sv[4];
#pragma unroll
            for (int j = 0; j < 4; ++j) {
                mem = (mem * 0.5f + xv[j]) - w;                    // ((mem*TAU)+x)-w
                float spike = (mem - 0.5f) > 0.0f ? 1.0f : 0.0f;   // ZIF forward
                w = 0.9f * w + 0.1f * (0.5f * mem + 0.5f * spike); // numpy order
                mem = mem - spike * 0.5f;                          // soft reset
                sv[j] = spike;
            }
            xs[c].x = sv[0]; xs[c].y = sv[1]; xs[c].z = sv[2]; xs[c].w = sv[3];
        }
    }

    // ---- store transpose: regs -> LDS rows -> stride-1 -> coalesced ------
#pragma unroll
    for (int c = 0; c < CHUNKS; ++c) tile[lane * CHUNKS + c] = xs[c];
    __syncthreads();  // 1-wave block: lgkm drain (+ cheap barrier if emitted)
#pragma unroll
    for (int k = 0; k < CHUNKS; ++k) {
        float4 s = tile[k * TPB + lane];
        ob[k * TPB + lane] = s;
    }
}

extern "C" void kernel_launch(void* const* d_in, const int* in_sizes, int n_in,
                              void* d_out, int out_size, void* d_ws, size_t ws_size,
                              hipStream_t stream) {
    const float* x = (const float*)d_in[0];
    float* out = (float*)d_out;
    int n_elem = in_sizes[0] / T_STEPS;       // 64*8192 = 524288
    int grid = n_elem / ELEMS;                // 8192 blocks, exact

    lif_kernel<<<grid, TPB, 0, stream>>>(x, out);
}